// Round 1
// 252.019 us; speedup vs baseline: 1.0121x; 1.0121x over previous
//
#include <hip/hip_runtime.h>

#define B 4
#define N 2048
#define V 12
#define C 50
#define P 16384      // 128*128 = 2^14
#define PSTRIDE 52   // floats per pool entry: 50 exps + sum + pad (208 B, 16B-aligned)

// ---------------------------------------------------------------------------
// Fused single streaming pass. TWO pixels per thread via float2 loads
// (8 B/lane coalescing sweet spot -- G13; dword streaming under-achieves BW).
// The 2x50 logits live in registers (~100 VGPR; __launch_bounds__(256,2)
// caps at 256, no spill). Mask-passing pixels (~7%) write exp-vector + sum
// as 13 float4 stores to pool[bv*P + p] (deterministic slot) and scatter
// the reference's exact key = argmax*P + p via 32-bit atomicMax.
// pred is read exactly once, fully coalesced. No second pass exists.
// ---------------------------------------------------------------------------
__global__ __launch_bounds__(256, 2) void k1_fused(
    const float* __restrict__ pred,      // (B*V, C, P)
    const int*   __restrict__ p2p,       // (B*V, P)
    const int*   __restrict__ parts_nb,  // (B,)
    int*         __restrict__ winner,    // (B*V*N), init -1
    float*       __restrict__ pool) {    // (B*V*P, PSTRIDE)
  int t  = blockIdx.x * 256 + threadIdx.x;   // grid exact: B*V*P/2 threads
  int p2 = t & (P / 2 - 1);                  // pixel-pair index
  int bv = t >> 13;                          // P/2 = 2^13
  int b  = bv / V;
  int p0 = p2 * 2;

  const float* pp = pred + (size_t)bv * C * P + p0;
  float2 l[C];
  #pragma unroll
  for (int c = 0; c < C; ++c)
    l[c] = *reinterpret_cast<const float2*>(pp + (size_t)c * P);  // 50 x dwordx2

  float m0 = l[0].x, m1 = l[0].y;
  int   a0 = 0,      a1 = 0;
  #pragma unroll
  for (int c = 1; c < C; ++c) {
    if (l[c].x > m0) { m0 = l[c].x; a0 = c; }
    if (l[c].y > m1) { m1 = l[c].y; a1 = c; }
  }

  int2 pt = *reinterpret_cast<const int2*>(p2p + (size_t)bv * P + p0);
  int  pn = parts_nb[b];

  if (pt.x != -1 && a0 >= 1 && a0 <= pn) {
    float* dst = pool + (size_t)(bv * P + p0) * PSTRIDE;
    float s = 0.f;
    #pragma unroll
    for (int c = 0; c < 48; c += 4) {
      float4 v = make_float4(__expf(l[c].x - m0),   __expf(l[c+1].x - m0),
                             __expf(l[c+2].x - m0), __expf(l[c+3].x - m0));
      s += (v.x + v.y) + (v.z + v.w);
      *reinterpret_cast<float4*>(dst + c) = v;
    }
    float e48 = __expf(l[48].x - m0), e49 = __expf(l[49].x - m0);
    s += e48 + e49;
    *reinterpret_cast<float4*>(dst + 48) = make_float4(e48, e49, s, 0.f);
    atomicMax(&winner[bv * N + pt.x], a0 * P + p0);   // reference's exact key
  }
  if (pt.y != -1 && a1 >= 1 && a1 <= pn) {
    float* dst = pool + (size_t)(bv * P + p0 + 1) * PSTRIDE;
    float s = 0.f;
    #pragma unroll
    for (int c = 0; c < 48; c += 4) {
      float4 v = make_float4(__expf(l[c].y - m1),   __expf(l[c+1].y - m1),
                             __expf(l[c+2].y - m1), __expf(l[c+3].y - m1));
      s += (v.x + v.y) + (v.z + v.w);
      *reinterpret_cast<float4*>(dst + c) = v;
    }
    float e48 = __expf(l[48].y - m1), e49 = __expf(l[49].y - m1);
    s += e48 + e49;
    *reinterpret_cast<float4*>(dst + 48) = make_float4(e48, e49, s, 0.f);
    atomicMax(&winner[bv * N + pt.y], a1 * P + p0 + 1);
  }
}

// ---------------------------------------------------------------------------
// Reduce: one wave per (b,n). key & (P-1) is the winning pixel -> pool slot.
// 12 winner keys hoisted up-front (full MLP). Lanes 0..49 read the 208 B
// entry contiguously (L3-hot: pool's written lines total ~12 MB). Output is
// transposed through LDS so each block stores out[b][c][n0..n0+3] as 16 B
// chunks (4x fewer store transactions than the lane=c 8 KB-stride scatter).
// ---------------------------------------------------------------------------
__global__ __launch_bounds__(256) void k3_reduce(
    const int*   __restrict__ winner,   // (B*V*N)
    const float* __restrict__ pool,     // (B*V*P, PSTRIDE)
    const float* __restrict__ vw,       // (B*V,)
    float*       __restrict__ out) {    // (B, C, N)
  __shared__ float sm[4][52];
  int w    = threadIdx.x >> 6;
  int lane = threadIdx.x & 63;
  int wid  = blockIdx.x * 4 + w;
  int b = wid >> 11;                    // N = 2048
  int n = wid & (N - 1);

  int keys[V];
  #pragma unroll
  for (int v = 0; v < V; ++v)
    keys[v] = winner[(b * V + v) * N + n];   // wave-uniform

  float acc = 0.f;
  int cnt = 0;
  #pragma unroll
  for (int v = 0; v < V; ++v) {
    int key = keys[v];
    if (key >= 0) {                          // wave-uniform branch
      int bv = b * V + v;
      const float* src = pool + (size_t)(bv * P + (key & (P - 1))) * PSTRIDE;
      float e = (lane < C) ? src[lane] : 0.f;
      float f = vw[bv] / src[C];             // sum stored at [50]
      acc += e * f;
      ++cnt;
    }
  }
  if (lane < C) sm[w][lane] = acc / (float)(cnt > 0 ? cnt : 1);
  __syncthreads();

  int tid = threadIdx.x;
  if (tid < 4 * C) {
    int c = tid >> 2, j = tid & 3;           // consecutive tid -> consecutive n
    int b_blk = (blockIdx.x * 4) >> 11;
    int n_blk = (blockIdx.x * 4) & (N - 1);
    out[((size_t)b_blk * C + c) * N + n_blk + j] = sm[j][c];
  }
}

extern "C" void kernel_launch(void* const* d_in, const int* in_sizes, int n_in,
                              void* d_out, int out_size, void* d_ws, size_t ws_size,
                              hipStream_t stream) {
  const float* pred  = (const float*)d_in[1];
  const int*   p2p   = (const int*)d_in[2];
  const float* vw    = (const float*)d_in[3];
  const int*   parts = (const int*)d_in[4];
  float* out = (float*)d_out;

  char* ws = (char*)d_ws;
  int*   winner = (int*)ws;                                  // 384 KiB
  float* pool   = (float*)(ws + (size_t)B * V * N * sizeof(int) + 128); // ~164 MiB

  hipMemsetAsync(winner, 0xFF, (size_t)B * V * N * sizeof(int), stream); // -1 fill

  int nthreads = B * V * P / 2;                              // 393216 (2 px/thread)
  k1_fused<<<nthreads / 256, 256, 0, stream>>>(
      pred, p2p, parts, winner, pool);

  k3_reduce<<<(B * N) / 4, 256, 0, stream>>>(winner, pool, vw, out);
}